// Round 14
// baseline (24.557 us; speedup 1.0000x reference)
//
#include <hip/hip_runtime.h>
#include <math.h>

#define EPSF 1e-20f
#define NEG_INF (-INFINITY)

struct TrueT  { static constexpr bool value = true;  };
struct FalseT { static constexpr bool value = false; };

__device__ __forceinline__ float softplusf(float x) {
    return fmaxf(x, 0.0f) + log1pf(expf(-fabsf(x)));
}
// fast reciprocal (v_rcp_f32) — ONLY for tolerance-protected epilogue math,
// never for argmax comparison values.
__device__ __forceinline__ float fastrcp(float x) {
    return __builtin_amdgcn_rcpf(x);
}

// Issue the 4 global loads for stage-B pair unit `unit` (pre-clamped to
// [0,1329]). Pure loads — no dependent compute, so they pipeline.
template<bool INTERIOR>
__device__ __forceinline__ void issue_pair_loads(
    int unit, const float* __restrict__ dp, const float* __restrict__ cdp,
    int rB, int cB,
    float& d0, float& d1, float& c0, float& c1)
{
    int wr = unit / 35;
    int t  = unit - wr * 35;
    int r  = rB + wr;
    int rl = INTERIOR ? r : (r < 0 ? 0 : (r > 255 ? 255 : r));
    int col0 = cB + 2 * t;                       // odd
    int c0i, c1i;
    if (INTERIOR) { c0i = col0; c1i = col0 + 1; }
    else {
        c0i = col0 < 0 ? 0 : (col0 > 255 ? 255 : col0);
        c1i = col0 + 1 < 0 ? 0 : (col0 + 1 > 255 ? 255 : col0 + 1);
    }
    const float* drow = dp  + rl * 256;
    const float* crow = cdp + rl * 256;
    d0 = drow[c0i];
    d1 = drow[c1i];
    c0 = crow[c0i];
    c1 = crow[c1i];
}

// One window's combine + propagation math (R13 stage-C body, factored).
// wlo[k] = pair (kw 0,1) of window row k; whi[k] = pair (kw 2,3).
// kh-major, kw-ascending strict > == reference flat argmax tie-break.
__device__ __forceinline__ float2 cell_combine(
    const float4 (&wlo)[4], const float4 (&whi)[4],
    float sv, float csv, float a0, float a1, float wp, float rwp1)
{
    float b1 = NEG_INF, d1 = NEG_INF, c1 = 1.0f;
    float b2 = NEG_INF, c2 = 0.f;
    #pragma unroll
    for (int k = 0; k < 4; ++k) {
        float4 w4 = wlo[k];
        float v1 = w4.x * w4.y;              // bit-exact recompute
        bool t1 = v1 > b1;
        b1 = t1 ? v1 : b1; d1 = t1 ? w4.x : d1; c1 = t1 ? w4.y : c1;
        bool t2 = w4.z > b2;
        b2 = t2 ? w4.z : b2; c2 = t2 ? w4.w : c2;
        w4 = whi[k];
        v1 = w4.x * w4.y;
        t1 = v1 > b1;
        b1 = t1 ? v1 : b1; d1 = t1 ? w4.x : d1; c1 = t1 ? w4.y : c1;
        t2 = w4.z > b2;
        b2 = t2 ? w4.z : b2; c2 = t2 ? w4.w : c2;
    }
    // winner's d recomputed from its exact quotient (tolerance-protected);
    // v2max==0 -> whole window cd==0 -> csfd==0 multiplies m out.
    float d2   = (b2 > 0.f) ? c2 * fastrcp(b2) : 0.f;
    float mm_  = fabsf(d2 * fastrcp(d1 + EPSF));
    float sfd  = (1.0f - a0 - a1) * mm_ + a0 * mm_ * mm_ + a1 * mm_ * mm_ * mm_;
    float csfd = c1 * c2;
    float den  = wp * csv + csfd;
    float spv  = (wp * csv * sv + csfd * sfd) * fastrcp(den + EPSF);
    float cp   = den * rwp1;
    return make_float2(cp * spv, cp);
}

// One block = 32x64 output tile of one (b,c) plane. 2048 blocks x 256 threads.
// Stage B: PAIR-granularity dual argmax (38x35 = 1330 units), 2-deep
//          software-pipelined; payload 16B W4=(d1,c1,v2,c2).
// Stage C: 2-CELL HORIZONTAL STRIPS (18x17 = 306 units): 12 ds_read_b128
//          per 2 cells (was 16); one aligned b128 lx write per strip.
// Stage D: 4-tap transposed depthwise conv + fused epilogue.
__global__ __launch_bounds__(256, 4) void fused_sndeconv(
    const float* __restrict__ d, const float* __restrict__ cd,
    const float* __restrict__ s, const float* __restrict__ cs,
    const float* __restrict__ w_s_from_d, const float* __restrict__ w_prop,
    const float* __restrict__ spatial_weight, const float* __restrict__ bias,
    float* __restrict__ s_out, float* __restrict__ cs_out)
{
    __shared__ float4 W4[38][35];        // (d1, c1, v2, c2)  20.8 KB
    __shared__ float2 lx[18][40];        // (x1, x2); stride 40 -> b128-aligned
    __shared__ float  sws[16];           // total ~26.7 KB

    const int tid = threadIdx.x;
    // XCD-chunked swizzle (2048 % 8 == 0 -> bijective)
    const int bid = blockIdx.x;
    const int blk = (bid & 7) * 256 + (bid >> 3);
    const int bc  = blk >> 5;            // plane 0..63
    const int tl  = blk & 31;
    const int by  = tl >> 2;             // 0..7  (32-row bands)
    const int bx  = tl & 3;              // 0..3  (64-col bands)
    const int c   = bc & 15;

    const int ib = by << 5;              // output row base
    const int jb = bx << 6;              // output col base
    const int mB = (ib >> 1) - 1;        // x-row base (18 rows)
    const int nB = (jb >> 1) - 1;        // x-col base (34 cols)
    const int rB = 2 * mB - 1;           // input row base (38 rows)
    const int cB = 2 * nB - 1;           // input col base (odd)

    if (tid < 16) sws[tid] = softplusf(spatial_weight[c * 16 + tid]);

    const float* dp  = d  + (size_t)bc * 65536;
    const float* cdp = cd + (size_t)bc * 65536;
    const float* sp  = s  + (size_t)bc * 16384;
    const float* csp = cs + (size_t)bc * 16384;

    const float a0 = w_s_from_d[0];
    const float a1 = w_s_from_d[1];
    const float wp = softplusf(w_prop[0]);
    const float rwp1 = fastrcp(wp + 1.0f);

    const bool interior = (by >= 1) && (by <= 6) && (bx >= 1) && (bx <= 2);

    auto runBC = [&](auto tag) {
        constexpr bool INT = decltype(tag)::value;

        // ---------- stage B: 2-deep pipelined pair argmax ----------
        float pd0[2], pd1[2], pc0[2], pc1[2];
        issue_pair_loads<INT>(tid, dp, cdp, rB, cB, pd0[0], pd1[0], pc0[0], pc1[0]);

        #pragma unroll
        for (int it = 0; it < 6; ++it) {
            const int cur = it & 1;
            const int nxt = cur ^ 1;
            if (it < 5) {
                int nu = tid + 256 * (it + 1);
                nu = nu < 1330 ? nu : 1329;      // clamp: safe redundant loads
                issue_pair_loads<INT>(nu, dp, cdp, rB, cB,
                                      pd0[nxt], pd1[nxt], pc0[nxt], pc1[nxt]);
            }
            int unit = tid + 256 * it;
            if (unit < 1330) {
                int wr = unit / 35;
                int t  = unit - wr * 35;
                bool mv0, mv1;
                if (INT) { mv0 = true; mv1 = true; }
                else {
                    int r    = rB + wr;
                    int col0 = cB + 2 * t;       // odd
                    bool rv  = (r >= 0) && (r < 256);
                    mv0 = rv && (col0 >= 0)  && (col0 <= 255);
                    mv1 = rv && (col0 >= -1) && (col0 <= 254);
                }
                float dv0 = pd0[cur], dv1 = pd1[cur];
                float cv0 = pc0[cur], cv1 = pc1[cur];

                // chain1 init (-inf,1): recomputed v1 = -inf can't win
                float b1 = NEG_INF, w1d = NEG_INF, w1c = 1.0f;
                float b2 = NEG_INF, w2c = 0.f;

                // element kw-even
                float v1 = mv0 ? dv0 * cv0          : NEG_INF;
                float v2 = mv0 ? cv0 / (dv0 + EPSF) : NEG_INF;  // EXACT div
                bool t1 = v1 > b1;
                b1 = t1 ? v1 : b1; w1d = t1 ? dv0 : w1d; w1c = t1 ? cv0 : w1c;
                bool t2 = v2 > b2;
                b2 = t2 ? v2 : b2; w2c = t2 ? cv0 : w2c;
                // element kw-odd
                v1 = mv1 ? dv1 * cv1          : NEG_INF;
                v2 = mv1 ? cv1 / (dv1 + EPSF) : NEG_INF;        // EXACT div
                t1 = v1 > b1;
                b1 = t1 ? v1 : b1; w1d = t1 ? dv1 : w1d; w1c = t1 ? cv1 : w1c;
                t2 = v2 > b2;
                b2 = t2 ? v2 : b2; w2c = t2 ? cv1 : w2c;

                W4[wr][t] = make_float4(w1d, w1c, b2, w2c);
            }
        }
        __syncthreads();

        // ---------- stage C: 2-cell horizontal strips ----------
        #pragma unroll
        for (int it = 0; it < 2; ++it) {
            int u = tid + 256 * it;
            if (u < 306) {
                int srow = u / 17;
                int sc   = u - srow * 17;
                int cn0  = 2 * sc;               // even, 0..32
                int m    = mB + srow;
                int n0   = nB + cn0;

                // 12 shared reads cover both cells (pairs cn0..cn0+2 x 4 rows)
                float4 wq[4][3];
                #pragma unroll
                for (int k = 0; k < 4; ++k) {
                    int row = 2 * srow + k;
                    wq[k][0] = W4[row][cn0];
                    wq[k][1] = W4[row][cn0 + 1];
                    wq[k][2] = W4[row][cn0 + 2];
                }
                float4 wA[4] = { wq[0][0], wq[1][0], wq[2][0], wq[3][0] };
                float4 wM[4] = { wq[0][1], wq[1][1], wq[2][1], wq[3][1] };
                float4 wZ[4] = { wq[0][2], wq[1][2], wq[2][2], wq[3][2] };

                float2 oA = make_float2(0.f, 0.f);
                float2 oB = make_float2(0.f, 0.f);
                bool mok = INT || (m >= 0 && m <= 127);
                if (mok) {
                    if (INT || (n0 >= 0 && n0 <= 127)) {
                        float sv  = sp [m * 128 + n0];
                        float csv = csp[m * 128 + n0];
                        oA = cell_combine(wA, wM, sv, csv, a0, a1, wp, rwp1);
                    }
                    if (INT || (n0 + 1 >= 0 && n0 + 1 <= 127)) {
                        float sv  = sp [m * 128 + n0 + 1];
                        float csv = csp[m * 128 + n0 + 1];
                        oB = cell_combine(wM, wZ, sv, csv, a0, a1, wp, rwp1);
                    }
                }
                // one aligned b128 write for both cells
                *(float4*)&lx[srow][cn0] = make_float4(oA.x, oA.y, oB.x, oB.y);
            }
        }
    };
    if (interior) runBC(TrueT{});
    else          runBC(FalseT{});
    __syncthreads();

    // ---------------- stage D: deconv + epilogue (8 outputs/thread) ----------------
    int ii = tid >> 3, jq = tid & 7;
    int i  = ib + ii;
    int u0 = (i + 1) & 1;
    int m0 = (i + 1 - u0) >> 1;
    int pr0 = m0 - mB;                    // 1..17
    int pr1 = pr0 - 1;                    // 0..16
    float rv0 = (m0 <= 127) ? 1.f : 0.f;
    float rv1 = (m0 >= 1)   ? 1.f : 0.f;

    float wA0 = sws[u0*4 + 0], wA1 = sws[u0*4 + 1], wA2 = sws[u0*4 + 2], wA3 = sws[u0*4 + 3];
    float wC0 = sws[(u0+2)*4 + 0], wC1 = sws[(u0+2)*4 + 1], wC2 = sws[(u0+2)*4 + 2], wC3 = sws[(u0+2)*4 + 3];
    float bv  = bias[c];

    int bb = 4 * jq;                      // float2 col base (even -> 16B aligned)
    float r1a[6], r2a[6], r1b[6], r2b[6];
    {
        const float4* p = (const float4*)&lx[pr0][bb];
        float4 q0 = p[0], q1 = p[1], q2 = p[2];
        r1a[0]=q0.x; r2a[0]=q0.y; r1a[1]=q0.z; r2a[1]=q0.w;
        r1a[2]=q1.x; r2a[2]=q1.y; r1a[3]=q1.z; r2a[3]=q1.w;
        r1a[4]=q2.x; r2a[4]=q2.y; r1a[5]=q2.z; r2a[5]=q2.w;
    }
    {
        const float4* p = (const float4*)&lx[pr1][bb];
        float4 q0 = p[0], q1 = p[1], q2 = p[2];
        r1b[0]=q0.x; r2b[0]=q0.y; r1b[1]=q0.z; r2b[1]=q0.w;
        r1b[2]=q1.x; r2b[2]=q1.y; r1b[3]=q1.z; r2b[3]=q1.w;
        r1b[4]=q2.x; r2b[4]=q2.y; r1b[5]=q2.z; r2b[5]=q2.w;
    }

    int n0b = (jb >> 1) + 4 * jq;
    size_t orow = (size_t)bc * 65536 + (size_t)i * 256 + jb + 8 * jq;

    float so[4], co[4];
    #pragma unroll
    for (int e = 0; e < 8; ++e) {
        const int v0 = (e + 1) & 1;
        const int hi = 1 + ((e + 1) >> 1);
        const int lo = hi - 1;
        float swa = v0 ? wA1 : wA0;       // (u0,   v0)
        float swb = v0 ? wA3 : wA2;       // (u0,   v0+2)
        float swc = v0 ? wC1 : wC0;       // (u0+2, v0)
        float swd = v0 ? wC3 : wC2;       // (u0+2, v0+2)

        float nom = swa*r1a[hi] + swb*r1a[lo] + swc*r1b[hi] + swd*r1b[lo];
        float den = swa*r2a[hi] + swb*r2a[lo] + swc*r2b[hi] + swd*r2b[lo];

        int n0 = n0b + ((e + 1) >> 1);
        float nvh = (n0 <= 127) ? 1.f : 0.f;
        float nvl = (n0 >= 1)   ? 1.f : 0.f;
        float cden = rv0 * (swa*nvh + swb*nvl) + rv1 * (swc*nvh + swd*nvl);

        so[e & 3] = nom * fastrcp(den + EPSF) + bv;
        co[e & 3] = den * fastrcp(cden);
        if ((e & 3) == 3) {
            *(float4*)(s_out  + orow + (e - 3)) = make_float4(so[0], so[1], so[2], so[3]);
            *(float4*)(cs_out + orow + (e - 3)) = make_float4(co[0], co[1], co[2], co[3]);
        }
    }
}

extern "C" void kernel_launch(void* const* d_in, const int* in_sizes, int n_in,
                              void* d_out, int out_size, void* d_ws, size_t ws_size,
                              hipStream_t stream) {
    const float* d    = (const float*)d_in[0];
    const float* cd   = (const float*)d_in[1];
    const float* s    = (const float*)d_in[2];
    const float* cs   = (const float*)d_in[3];
    const float* wsd  = (const float*)d_in[4];
    const float* wpr  = (const float*)d_in[5];
    const float* spw  = (const float*)d_in[6];
    const float* bias = (const float*)d_in[7];

    float* out  = (float*)d_out;
    float* s_o  = out;
    float* cs_o = out + (size_t)4 * 16 * 256 * 256;

    // 64 planes x 32 tiles (8x4 of 32x64 outputs) = 2048 blocks
    fused_sndeconv<<<2048, 256, 0, stream>>>(d, cd, s, cs, wsd, wpr, spw, bias, s_o, cs_o);
}

// Round 15
// 22.221 us; speedup vs baseline: 1.1051x; 1.1051x over previous
//
#include <hip/hip_runtime.h>
#include <math.h>

#define EPSF 1e-20f
#define NEG_INF (-INFINITY)

struct TrueT  { static constexpr bool value = true;  };
struct FalseT { static constexpr bool value = false; };

__device__ __forceinline__ float softplusf(float x) {
    return fmaxf(x, 0.0f) + log1pf(expf(-fabsf(x)));
}
// fast reciprocal (v_rcp_f32) — ONLY for tolerance-protected epilogue math,
// never for argmax comparison values.
__device__ __forceinline__ float fastrcp(float x) {
    return __builtin_amdgcn_rcpf(x);
}

// Issue the 4 global loads for stage-B pair unit `unit` (pre-clamped to
// [0,1329]). Pure loads — no dependent compute, so they pipeline.
template<bool INTERIOR>
__device__ __forceinline__ void issue_pair_loads(
    int unit, const float* __restrict__ dp, const float* __restrict__ cdp,
    int rB, int cB,
    float& d0, float& d1, float& c0, float& c1)
{
    int wr = unit / 35;
    int t  = unit - wr * 35;
    int r  = rB + wr;
    int rl = INTERIOR ? r : (r < 0 ? 0 : (r > 255 ? 255 : r));
    int col0 = cB + 2 * t;                       // odd
    int c0i, c1i;
    if (INTERIOR) { c0i = col0; c1i = col0 + 1; }
    else {
        c0i = col0 < 0 ? 0 : (col0 > 255 ? 255 : col0);
        c1i = col0 + 1 < 0 ? 0 : (col0 + 1 > 255 ? 255 : col0 + 1);
    }
    const float* drow = dp  + rl * 256;
    const float* crow = cdp + rl * 256;
    d0 = drow[c0i];
    d1 = drow[c1i];
    c0 = crow[c0i];
    c1 = crow[c1i];
}

// One block = 32x64 output tile of one (b,c) plane. 2048 blocks x 256 threads.
// Stage B: PAIR-granularity dual argmax (38 rows x 35 col-pairs = 1330 units),
//          2-deep software-pipelined. Payload 16B: W4=(d1,c1,v2,c2), one
//          ds_write_b128. chain-1 value recomputed as d1*c1 downstream
//          (bit-exact); chain-2 winner's d recomputed as c2*rcp(v2) in C
//          (tolerance-protected, v2>0 guarded).
// Stage C: PER-CELL combine (R13 structure — R14's 2-cell strips regressed:
//          fewer/fatter units lose to more/thinner units here).
// Stage D: 4-tap transposed depthwise conv + fused epilogue.
// lx stride 36 (was 38): LDS 26528 B < 160KB/6 -> 6 blocks/CU LDS-capped.
__global__ __launch_bounds__(256, 4) void fused_sndeconv(
    const float* __restrict__ d, const float* __restrict__ cd,
    const float* __restrict__ s, const float* __restrict__ cs,
    const float* __restrict__ w_s_from_d, const float* __restrict__ w_prop,
    const float* __restrict__ spatial_weight, const float* __restrict__ bias,
    float* __restrict__ s_out, float* __restrict__ cs_out)
{
    __shared__ float4 W4[38][35];        // (d1, c1, v2, c2)  20.8 KB
    __shared__ float2 lx[18][36];        // (x1, x2) interleaved; 5.1 KB
    __shared__ float  sws[16];           // total 26528 B -> 6 blocks/CU

    const int tid = threadIdx.x;
    // XCD-chunked swizzle (2048 % 8 == 0 -> bijective): vertical neighbor
    // tiles co-resident on one XCD L2.
    const int bid = blockIdx.x;
    const int blk = (bid & 7) * 256 + (bid >> 3);
    const int bc  = blk >> 5;            // plane 0..63
    const int tl  = blk & 31;
    const int by  = tl >> 2;             // 0..7  (32-row bands)
    const int bx  = tl & 3;              // 0..3  (64-col bands)
    const int c   = bc & 15;

    const int ib = by << 5;              // output row base
    const int jb = bx << 6;              // output col base
    const int mB = (ib >> 1) - 1;        // x-row base (18 rows)
    const int nB = (jb >> 1) - 1;        // x-col base (34 cols)
    const int rB = 2 * mB - 1;           // input row base (38 rows)
    const int cB = 2 * nB - 1;           // input col base (odd)

    if (tid < 16) sws[tid] = softplusf(spatial_weight[c * 16 + tid]);

    const float* dp  = d  + (size_t)bc * 65536;
    const float* cdp = cd + (size_t)bc * 65536;
    const float* sp  = s  + (size_t)bc * 16384;
    const float* csp = cs + (size_t)bc * 16384;

    const float a0 = w_s_from_d[0];
    const float a1 = w_s_from_d[1];
    const float wp = softplusf(w_prop[0]);
    const float rwp1 = fastrcp(wp + 1.0f);

    const bool interior = (by >= 1) && (by <= 6) && (bx >= 1) && (bx <= 2);

    auto runBC = [&](auto tag) {
        constexpr bool INT = decltype(tag)::value;

        // ---------- stage B: 2-deep pipelined pair argmax ----------
        float pd0[2], pd1[2], pc0[2], pc1[2];

        // prologue: unit for it=0 (tid < 256 < 1330, no clamp needed)
        issue_pair_loads<INT>(tid, dp, cdp, rB, cB, pd0[0], pd1[0], pc0[0], pc1[0]);

        #pragma unroll
        for (int it = 0; it < 6; ++it) {
            const int cur = it & 1;
            const int nxt = cur ^ 1;
            if (it < 5) {                        // compile-time after unroll
                int nu = tid + 256 * (it + 1);
                nu = nu < 1330 ? nu : 1329;      // clamp: safe redundant loads
                issue_pair_loads<INT>(nu, dp, cdp, rB, cB,
                                      pd0[nxt], pd1[nxt], pc0[nxt], pc1[nxt]);
            }
            int unit = tid + 256 * it;
            if (unit < 1330) {
                int wr = unit / 35;
                int t  = unit - wr * 35;
                bool mv0, mv1;
                if (INT) { mv0 = true; mv1 = true; }
                else {
                    int r    = rB + wr;
                    int col0 = cB + 2 * t;       // odd
                    bool rv  = (r >= 0) && (r < 256);
                    mv0 = rv && (col0 >= 0)  && (col0 <= 255);
                    mv1 = rv && (col0 >= -1) && (col0 <= 254);
                }
                float dv0 = pd0[cur], dv1 = pd1[cur];
                float cv0 = pc0[cur], cv1 = pc1[cur];

                // chain1 init (-inf,1): recomputed v1 = -inf can't win
                float b1 = NEG_INF, w1d = NEG_INF, w1c = 1.0f;
                float b2 = NEG_INF, w2c = 0.f;

                // element kw-even
                float v1 = mv0 ? dv0 * cv0          : NEG_INF;
                float v2 = mv0 ? cv0 / (dv0 + EPSF) : NEG_INF;  // EXACT div
                bool t1 = v1 > b1;
                b1 = t1 ? v1 : b1; w1d = t1 ? dv0 : w1d; w1c = t1 ? cv0 : w1c;
                bool t2 = v2 > b2;
                b2 = t2 ? v2 : b2; w2c = t2 ? cv0 : w2c;
                // element kw-odd
                v1 = mv1 ? dv1 * cv1          : NEG_INF;
                v2 = mv1 ? cv1 / (dv1 + EPSF) : NEG_INF;        // EXACT div
                t1 = v1 > b1;
                b1 = t1 ? v1 : b1; w1d = t1 ? dv1 : w1d; w1c = t1 ? cv1 : w1c;
                t2 = v2 > b2;
                b2 = t2 ? v2 : b2; w2c = t2 ? cv1 : w2c;

                W4[wr][t] = make_float4(w1d, w1c, b2, w2c);
            }
        }
        __syncthreads();

        // ---------- stage C: 2-pair x 4-row combine + prop math ----------
        #pragma unroll
        for (int it = 0; it < 3; ++it) {
            int unit = tid + 256 * it;
            if (unit < 612) {
                int cmr = unit / 34;
                int cn  = unit - cmr * 34;
                int m   = mB + cmr;
                int n   = nB + cn;
                if (!INT && (m < 0 || m > 127 || n < 0 || n > 127)) {
                    lx[cmr][cn] = make_float2(0.f, 0.f);
                } else {
                    // global loads first (overlap with LDS combine below)
                    float sv  = sp [m * 128 + n];
                    float csv = csp[m * 128 + n];

                    float b1 = NEG_INF, d1 = NEG_INF, c1 = 1.0f;
                    float b2 = NEG_INF, c2 = 0.f;
                    // kh-major, kw-ascending: row k, pair cn then cn+1
                    #pragma unroll
                    for (int k = 0; k < 4; ++k) {
                        int row = 2 * cmr + k;
                        #pragma unroll
                        for (int dt = 0; dt < 2; ++dt) {
                            float4 w4 = W4[row][cn + dt];
                            float v1 = w4.x * w4.y;          // bit-exact recompute
                            bool t1 = v1 > b1;
                            b1 = t1 ? v1 : b1; d1 = t1 ? w4.x : d1; c1 = t1 ? w4.y : c1;
                            bool t2 = w4.z > b2;
                            b2 = t2 ? w4.z : b2; c2 = t2 ? w4.w : c2;
                        }
                    }

                    // winner's d recomputed from its exact quotient:
                    // d2 ~ (d+eps)(1 +- 2^-22); if v2max==0 the whole window
                    // has cd==0 -> csfd==0 multiplies m out -> exact anyway.
                    float d2   = (b2 > 0.f) ? c2 * fastrcp(b2) : 0.f;
                    float mm_  = fabsf(d2 * fastrcp(d1 + EPSF));
                    float sfd  = (1.0f - a0 - a1) * mm_ + a0 * mm_ * mm_ + a1 * mm_ * mm_ * mm_;
                    float csfd = c1 * c2;
                    float den  = wp * csv + csfd;
                    float spv  = (wp * csv * sv + csfd * sfd) * fastrcp(den + EPSF);
                    float cp   = den * rwp1;
                    lx[cmr][cn] = make_float2(cp * spv, cp);
                }
            }
        }
    };
    if (interior) runBC(TrueT{});
    else          runBC(FalseT{});
    __syncthreads();

    // ---------------- stage D: deconv + epilogue (8 outputs/thread) ----------------
    int ii = tid >> 3, jq = tid & 7;
    int i  = ib + ii;
    int u0 = (i + 1) & 1;
    int m0 = (i + 1 - u0) >> 1;
    int pr0 = m0 - mB;                    // 1..17
    int pr1 = pr0 - 1;                    // 0..16
    float rv0 = (m0 <= 127) ? 1.f : 0.f;
    float rv1 = (m0 >= 1)   ? 1.f : 0.f;

    float wA0 = sws[u0*4 + 0], wA1 = sws[u0*4 + 1], wA2 = sws[u0*4 + 2], wA3 = sws[u0*4 + 3];
    float wC0 = sws[(u0+2)*4 + 0], wC1 = sws[(u0+2)*4 + 1], wC2 = sws[(u0+2)*4 + 2], wC3 = sws[(u0+2)*4 + 3];
    float bv  = bias[c];

    int bb = 4 * jq;                      // float2 col base (even -> 16B aligned)
    float r1a[6], r2a[6], r1b[6], r2b[6];
    {
        const float4* p = (const float4*)&lx[pr0][bb];
        float4 q0 = p[0], q1 = p[1], q2 = p[2];
        r1a[0]=q0.x; r2a[0]=q0.y; r1a[1]=q0.z; r2a[1]=q0.w;
        r1a[2]=q1.x; r2a[2]=q1.y; r1a[3]=q1.z; r2a[3]=q1.w;
        r1a[4]=q2.x; r2a[4]=q2.y; r1a[5]=q2.z; r2a[5]=q2.w;
    }
    {
        const float4* p = (const float4*)&lx[pr1][bb];
        float4 q0 = p[0], q1 = p[1], q2 = p[2];
        r1b[0]=q0.x; r2b[0]=q0.y; r1b[1]=q0.z; r2b[1]=q0.w;
        r1b[2]=q1.x; r2b[2]=q1.y; r1b[3]=q1.z; r2b[3]=q1.w;
        r1b[4]=q2.x; r2b[4]=q2.y; r1b[5]=q2.z; r2b[5]=q2.w;
    }

    int n0b = (jb >> 1) + 4 * jq;
    size_t orow = (size_t)bc * 65536 + (size_t)i * 256 + jb + 8 * jq;

    float so[4], co[4];
    #pragma unroll
    for (int e = 0; e < 8; ++e) {
        const int v0 = (e + 1) & 1;
        const int hi = 1 + ((e + 1) >> 1);
        const int lo = hi - 1;
        float swa = v0 ? wA1 : wA0;       // (u0,   v0)
        float swb = v0 ? wA3 : wA2;       // (u0,   v0+2)
        float swc = v0 ? wC1 : wC0;       // (u0+2, v0)
        float swd = v0 ? wC3 : wC2;       // (u0+2, v0+2)

        float nom = swa*r1a[hi] + swb*r1a[lo] + swc*r1b[hi] + swd*r1b[lo];
        float den = swa*r2a[hi] + swb*r2a[lo] + swc*r2b[hi] + swd*r2b[lo];

        int n0 = n0b + ((e + 1) >> 1);
        float nvh = (n0 <= 127) ? 1.f : 0.f;
        float nvl = (n0 >= 1)   ? 1.f : 0.f;
        float cden = rv0 * (swa*nvh + swb*nvl) + rv1 * (swc*nvh + swd*nvl);

        so[e & 3] = nom * fastrcp(den + EPSF) + bv;
        co[e & 3] = den * fastrcp(cden);
        if ((e & 3) == 3) {
            *(float4*)(s_out  + orow + (e - 3)) = make_float4(so[0], so[1], so[2], so[3]);
            *(float4*)(cs_out + orow + (e - 3)) = make_float4(co[0], co[1], co[2], co[3]);
        }
    }
}

extern "C" void kernel_launch(void* const* d_in, const int* in_sizes, int n_in,
                              void* d_out, int out_size, void* d_ws, size_t ws_size,
                              hipStream_t stream) {
    const float* d    = (const float*)d_in[0];
    const float* cd   = (const float*)d_in[1];
    const float* s    = (const float*)d_in[2];
    const float* cs   = (const float*)d_in[3];
    const float* wsd  = (const float*)d_in[4];
    const float* wpr  = (const float*)d_in[5];
    const float* spw  = (const float*)d_in[6];
    const float* bias = (const float*)d_in[7];

    float* out  = (float*)d_out;
    float* s_o  = out;
    float* cs_o = out + (size_t)4 * 16 * 256 * 256;

    // 64 planes x 32 tiles (8x4 of 32x64 outputs) = 2048 blocks
    fused_sndeconv<<<2048, 256, 0, stream>>>(d, cd, s, cs, wsd, wpr, spw, bias, s_o, cs_o);
}